// Round 1
// baseline (958.134 us; speedup 1.0000x reference)
//
#include <hip/hip_runtime.h>

using u16 = unsigned short;
using short8 = __attribute__((ext_vector_type(8))) short;
using floatx4 = __attribute__((ext_vector_type(4))) float;

__device__ __forceinline__ u16 f2bf(float f) {
    union { float f; unsigned u; } v; v.f = f;
    unsigned u = v.u + 0x7FFFu + ((v.u >> 16) & 1u);
    return (u16)(u >> 16);
}
__device__ __forceinline__ float bf2f(u16 h) {
    union { unsigned u; float f; } v; v.u = ((unsigned)h) << 16;
    return v.f;
}

// ---------------- conversions fp32 -> bf16 (plain and hi/lo split) ----------------
__global__ void conv_split_kernel(const float* __restrict__ src, u16* __restrict__ hi,
                                  u16* __restrict__ lo, int n) {
    int i = (blockIdx.x * blockDim.x + threadIdx.x) * 4;
    if (i >= n) return;
    float4 v = *reinterpret_cast<const float4*>(src + i);
    ushort4 h, l;
    h.x = f2bf(v.x); l.x = f2bf(v.x - bf2f(h.x));
    h.y = f2bf(v.y); l.y = f2bf(v.y - bf2f(h.y));
    h.z = f2bf(v.z); l.z = f2bf(v.z - bf2f(h.z));
    h.w = f2bf(v.w); l.w = f2bf(v.w - bf2f(h.w));
    *reinterpret_cast<ushort4*>(hi + i) = h;
    *reinterpret_cast<ushort4*>(lo + i) = l;
}

__global__ void conv_kernel(const float* __restrict__ src, u16* __restrict__ dst, int n) {
    int i = (blockIdx.x * blockDim.x + threadIdx.x) * 4;
    if (i >= n) return;
    float4 v = *reinterpret_cast<const float4*>(src + i);
    ushort4 h;
    h.x = f2bf(v.x); h.y = f2bf(v.y); h.z = f2bf(v.z); h.w = f2bf(v.w);
    *reinterpret_cast<ushort4*>(dst + i) = h;
}

// ---------------- GEMM: C[M,N] = A[M,K] @ B[N,K]^T  (bf16 in, fp32 acc) ----------
// M=16384, N=1024, K=1024. 128x128 tile, BK=32, 256 threads (4 waves, 64x64/wave).
// SPLIT: A,B given as hi+lo bf16 planes; C ~= Ah*Bh + Al*Bh + Ah*Bl.
#define GK 1024
#define GN 1024
#define LDT 40  // 32 + 8 pad (keeps 16B alignment, 2-way-only conflicts)

template<bool SPLIT>
__global__ __launch_bounds__(256)
void gemm_bt(const u16* __restrict__ Ah, const u16* __restrict__ Al,
             const u16* __restrict__ Bh, const u16* __restrict__ Bl,
             u16* __restrict__ Cb, float* __restrict__ Cf,
             const float* __restrict__ bias, float scale)
{
    __shared__ u16 As[SPLIT ? 2 : 1][128 * LDT];
    __shared__ u16 Bs[SPLIT ? 2 : 1][128 * LDT];

    const int tid  = threadIdx.x;
    const int lane = tid & 63, wave = tid >> 6;
    const int quad = lane >> 4, l15 = lane & 15;
    const int wr = wave >> 1, wc = wave & 1;
    const int bm = blockIdx.y * 128, bn = blockIdx.x * 128;

    floatx4 acc[4][4];
#pragma unroll
    for (int mt = 0; mt < 4; ++mt)
#pragma unroll
        for (int nt = 0; nt < 4; ++nt)
#pragma unroll
            for (int r = 0; r < 4; ++r) acc[mt][nt][r] = 0.f;

    const int sr = tid >> 2;         // 0..63
    const int sc = (tid & 3) * 8;    // 0,8,16,24

    for (int kt = 0; kt < GK; kt += 32) {
        __syncthreads();
#pragma unroll
        for (int p = 0; p < 2; ++p) {
            int r = sr + p * 64;
            *reinterpret_cast<short8*>(&As[0][r * LDT + sc]) =
                *reinterpret_cast<const short8*>(Ah + (size_t)(bm + r) * GK + kt + sc);
            *reinterpret_cast<short8*>(&Bs[0][r * LDT + sc]) =
                *reinterpret_cast<const short8*>(Bh + (size_t)(bn + r) * GK + kt + sc);
            if (SPLIT) {
                *reinterpret_cast<short8*>(&As[1][r * LDT + sc]) =
                    *reinterpret_cast<const short8*>(Al + (size_t)(bm + r) * GK + kt + sc);
                *reinterpret_cast<short8*>(&Bs[1][r * LDT + sc]) =
                    *reinterpret_cast<const short8*>(Bl + (size_t)(bn + r) * GK + kt + sc);
            }
        }
        __syncthreads();

        short8 a_h[4], b_h[4];
#pragma unroll
        for (int mt = 0; mt < 4; ++mt)
            a_h[mt] = *reinterpret_cast<const short8*>(&As[0][(wr * 64 + mt * 16 + l15) * LDT + quad * 8]);
#pragma unroll
        for (int nt = 0; nt < 4; ++nt)
            b_h[nt] = *reinterpret_cast<const short8*>(&Bs[0][(wc * 64 + nt * 16 + l15) * LDT + quad * 8]);
#pragma unroll
        for (int mt = 0; mt < 4; ++mt)
#pragma unroll
            for (int nt = 0; nt < 4; ++nt)
                acc[mt][nt] = __builtin_amdgcn_mfma_f32_16x16x32_bf16(a_h[mt], b_h[nt], acc[mt][nt], 0, 0, 0);

        if (SPLIT) {
            short8 a_l[4], b_l[4];
#pragma unroll
            for (int mt = 0; mt < 4; ++mt)
                a_l[mt] = *reinterpret_cast<const short8*>(&As[1][(wr * 64 + mt * 16 + l15) * LDT + quad * 8]);
#pragma unroll
            for (int nt = 0; nt < 4; ++nt)
                b_l[nt] = *reinterpret_cast<const short8*>(&Bs[1][(wc * 64 + nt * 16 + l15) * LDT + quad * 8]);
#pragma unroll
            for (int mt = 0; mt < 4; ++mt)
#pragma unroll
                for (int nt = 0; nt < 4; ++nt) {
                    acc[mt][nt] = __builtin_amdgcn_mfma_f32_16x16x32_bf16(a_l[mt], b_h[nt], acc[mt][nt], 0, 0, 0);
                    acc[mt][nt] = __builtin_amdgcn_mfma_f32_16x16x32_bf16(a_h[mt], b_l[nt], acc[mt][nt], 0, 0, 0);
                }
        }
    }

    // epilogue: C/D layout col = lane&15, row = quad*4 + reg
#pragma unroll
    for (int mt = 0; mt < 4; ++mt)
#pragma unroll
        for (int nt = 0; nt < 4; ++nt)
#pragma unroll
            for (int r = 0; r < 4; ++r) {
                int row = bm + wr * 64 + mt * 16 + quad * 4 + r;
                int col = bn + wc * 64 + nt * 16 + l15;
                float v = acc[mt][nt][r] * scale;
                if (bias) v += bias[col];
                size_t off = (size_t)row * GN + col;
                if (Cf) Cf[off] = v;
                else Cb[off] = f2bf(v);
            }
}

// ---------------- fused flash attention ----------------
// grid (qt=16, h=8, b=16); block 256 = 4 waves; wave handles 16 q rows, block 64.
// Q,K pre-scaled by k^-0.25 in projection GEMMs.
#define LKS 136  // K lds stride (128+8)
#define LVS 72   // Vt lds stride (64+8)
#define LPS 72   // P lds stride (64+8)

__global__ __launch_bounds__(256)
void attn_kernel(const u16* __restrict__ Q, const u16* __restrict__ Kk,
                 const u16* __restrict__ V, u16* __restrict__ AO)
{
    __shared__ u16 Ks[64 * LKS];
    __shared__ u16 Vts[128 * LVS];
    __shared__ u16 Ps[4][16 * LPS];

    const int tid  = threadIdx.x;
    const int lane = tid & 63, wave = tid >> 6;
    const int quad = lane >> 4, l15 = lane & 15;
    const int qt = blockIdx.x, h = blockIdx.y, b = blockIdx.z;

    // Q fragments (A layout: m = lane&15, k = s*32 + quad*8 + j), kept in regs
    short8 qf[4];
    {
        int qrow = b * 1024 + qt * 64 + wave * 16 + l15;
        const u16* qp = Q + (size_t)qrow * 1024 + h * 128;
#pragma unroll
        for (int s = 0; s < 4; ++s)
            qf[s] = *reinterpret_cast<const short8*>(qp + s * 32 + quad * 8);
    }

    float m_r[4], l_r[4];
    floatx4 oacc[8];
#pragma unroll
    for (int r = 0; r < 4; ++r) { m_r[r] = -3.0e38f; l_r[r] = 0.f; }
#pragma unroll
    for (int nt = 0; nt < 8; ++nt)
#pragma unroll
        for (int r = 0; r < 4; ++r) oacc[nt][r] = 0.f;

    const int vdim = tid & 127, vkb = (tid >> 7) * 8;

    for (int kt2 = 0; kt2 < 16; ++kt2) {
        __syncthreads();  // protect restaging vs previous iteration's reads
        // stage K tile [64 keys x 128 dims], row-major, 16B chunks
#pragma unroll
        for (int i = 0; i < 4; ++i) {
            int chunk = tid + i * 256;
            int r = chunk >> 4, c = (chunk & 15) * 8;
            *reinterpret_cast<short8*>(&Ks[r * LKS + c]) =
                *reinterpret_cast<const short8*>(Kk + (size_t)(b * 1024 + kt2 * 64 + r) * 1024 + h * 128 + c);
        }
        // stage V transposed: Vts[dim][key]
#pragma unroll
        for (int p = 0; p < 4; ++p) {
            int kb = vkb + p * 16;
            short8 vv;
#pragma unroll
            for (int j = 0; j < 8; ++j)
                vv[j] = (short)V[(size_t)(b * 1024 + kt2 * 64 + kb + j) * 1024 + h * 128 + vdim];
            *reinterpret_cast<short8*>(&Vts[vdim * LVS + kb]) = vv;
        }
        __syncthreads();

        // S = Q K^T  (16 x 64 per wave)
        floatx4 sacc[4];
#pragma unroll
        for (int nt = 0; nt < 4; ++nt)
#pragma unroll
            for (int r = 0; r < 4; ++r) sacc[nt][r] = 0.f;
#pragma unroll
        for (int s = 0; s < 4; ++s)
#pragma unroll
            for (int nt = 0; nt < 4; ++nt) {
                short8 bfr = *reinterpret_cast<const short8*>(&Ks[(nt * 16 + l15) * LKS + s * 32 + quad * 8]);
                sacc[nt] = __builtin_amdgcn_mfma_f32_16x16x32_bf16(qf[s], bfr, sacc[nt], 0, 0, 0);
            }

        // online softmax: row = quad*4 + r, 16 lanes of a quad hold the row
        float alpha[4];
#pragma unroll
        for (int r = 0; r < 4; ++r) {
            float mx = sacc[0][r];
#pragma unroll
            for (int nt = 1; nt < 4; ++nt) mx = fmaxf(mx, sacc[nt][r]);
            mx = fmaxf(mx, __shfl_xor(mx, 1));
            mx = fmaxf(mx, __shfl_xor(mx, 2));
            mx = fmaxf(mx, __shfl_xor(mx, 4));
            mx = fmaxf(mx, __shfl_xor(mx, 8));
            float mn = fmaxf(m_r[r], mx);
            alpha[r] = __expf(m_r[r] - mn);
            m_r[r] = mn;
            float sum = 0.f;
#pragma unroll
            for (int nt = 0; nt < 4; ++nt) {
                float pv = __expf(sacc[nt][r] - mn);
                sacc[nt][r] = pv;
                sum += pv;
            }
            sum += __shfl_xor(sum, 1);
            sum += __shfl_xor(sum, 2);
            sum += __shfl_xor(sum, 4);
            sum += __shfl_xor(sum, 8);
            l_r[r] = l_r[r] * alpha[r] + sum;
        }
#pragma unroll
        for (int nt = 0; nt < 8; ++nt)
#pragma unroll
            for (int r = 0; r < 4; ++r) oacc[nt][r] *= alpha[r];

        // P: C-layout -> LDS -> A-layout
#pragma unroll
        for (int nt = 0; nt < 4; ++nt)
#pragma unroll
            for (int r = 0; r < 4; ++r)
                Ps[wave][(quad * 4 + r) * LPS + nt * 16 + l15] = f2bf(sacc[nt][r]);
        __syncthreads();

        // O += P V
#pragma unroll
        for (int ks = 0; ks < 2; ++ks) {
            short8 pa = *reinterpret_cast<const short8*>(&Ps[wave][l15 * LPS + ks * 32 + quad * 8]);
#pragma unroll
            for (int nt = 0; nt < 8; ++nt) {
                short8 bv = *reinterpret_cast<const short8*>(&Vts[(nt * 16 + l15) * LVS + ks * 32 + quad * 8]);
                oacc[nt] = __builtin_amdgcn_mfma_f32_16x16x32_bf16(pa, bv, oacc[nt], 0, 0, 0);
            }
        }
    }

    // epilogue: normalize and store bf16
#pragma unroll
    for (int r = 0; r < 4; ++r) {
        float inv = 1.0f / l_r[r];
        int row = b * 1024 + qt * 64 + wave * 16 + quad * 4 + r;
#pragma unroll
        for (int nt = 0; nt < 8; ++nt) {
            int col = h * 128 + nt * 16 + l15;
            AO[(size_t)row * 1024 + col] = f2bf(oacc[nt][r] * inv);
        }
    }
}

// ---------------- pooling: mean + max over L ----------------
__global__ void pool_kernel(const float* __restrict__ O, float* __restrict__ P) {
    int b = blockIdx.x, d = threadIdx.x;  // block 1024
    const float* p = O + (size_t)b * 1024 * 1024 + d;
    float s = 0.f, mx = -3.0e38f;
    for (int l = 0; l < 1024; ++l) {
        float v = p[(size_t)l * 1024];
        s += v;
        mx = fmaxf(mx, v);
    }
    P[b * 1024 + d] = s * (1.0f / 1024.0f) + mx;
}

// ---------------- final MLP: [16,1024] @ [64,1024]^T + bias ----------------
__global__ void mlp_kernel(const float* __restrict__ P, const float* __restrict__ W,
                           const float* __restrict__ bias, float* __restrict__ out) {
    int b = blockIdx.x, o = threadIdx.x;  // block 64
    const float* pr = P + b * 1024;
    const float* wr = W + o * 1024;
    float s = bias[o];
    for (int d = 0; d < 1024; ++d) s += pr[d] * wr[d];
    out[b * 64 + o] = s;
}

extern "C" void kernel_launch(void* const* d_in, const int* in_sizes, int n_in,
                              void* d_out, int out_size, void* d_ws, size_t ws_size,
                              hipStream_t stream) {
    const float* x0 = (const float*)d_in[0];
    const float* x1 = (const float*)d_in[1];
    const float* x2 = (const float*)d_in[2];
    // d_in[3] support, d_in[4] mask: unused by the reference computation
    const float* Wk = (const float*)d_in[5];
    const float* Wq = (const float*)d_in[6];
    const float* Wv = (const float*)d_in[7];
    const float* Wu = (const float*)d_in[8];
    const float* bu = (const float*)d_in[9];
    const float* Wmlp = (const float*)d_in[10];
    const float* bmlp = (const float*)d_in[11];
    float* out = (float*)d_out;

    // workspace layout (bytes). outU (64MB fp32) overlays xh+xl (dead by then).
    char* ws = (char*)d_ws;
    const size_t MB32 = 33554432ull;
    u16* xh = (u16*)(ws);
    u16* xl = (u16*)(ws + MB32);
    float* outU = (float*)(ws);  // overlay, used after xh/xl are dead
    size_t wo = 2 * MB32;
    u16* Wkh = (u16*)(ws + wo); wo += 2097152;
    u16* Wkl = (u16*)(ws + wo); wo += 2097152;
    u16* Wqh = (u16*)(ws + wo); wo += 2097152;
    u16* Wql = (u16*)(ws + wo); wo += 2097152;
    u16* Wvh = (u16*)(ws + wo); wo += 2097152;
    u16* Wuh = (u16*)(ws + wo); wo += 2097152;
    u16* Qb = (u16*)(ws + wo); wo += MB32;
    u16* Kb = (u16*)(ws + wo); wo += MB32;
    u16* Vb = (u16*)(ws + wo); wo += MB32;
    u16* AOb = (u16*)(ws + wo); wo += MB32;
    float* pooled = (float*)(ws + wo); wo += 65536;
    if (ws_size < wo) return;  // insufficient workspace: fail loudly via wrong output

    const float scale = 0.29730177875068026f;  // 128^(-0.25), applied to both q and k
    const int nX = 16 * 1024 * 1024;
    const int nW = 1024 * 1024;

    conv_split_kernel<<<nW / 1024, 256, 0, stream>>>(Wk, Wkh, Wkl, nW);
    conv_split_kernel<<<nW / 1024, 256, 0, stream>>>(Wq, Wqh, Wql, nW);
    conv_kernel<<<nW / 1024, 256, 0, stream>>>(Wv, Wvh, nW);
    conv_kernel<<<nW / 1024, 256, 0, stream>>>(Wu, Wuh, nW);

    dim3 ggrid(8, 128);  // N/128, M/128
    // q = (x2 @ Wk^T) * scale   [split for accuracy: feeds softmax logits]
    conv_split_kernel<<<nX / 1024, 256, 0, stream>>>(x2, xh, xl, nX);
    gemm_bt<true><<<ggrid, 256, 0, stream>>>(xh, xl, Wkh, Wkl, Qb, nullptr, nullptr, scale);
    // k = (x1 @ Wq^T) * scale
    conv_split_kernel<<<nX / 1024, 256, 0, stream>>>(x1, xh, xl, nX);
    gemm_bt<true><<<ggrid, 256, 0, stream>>>(xh, xl, Wqh, Wql, Kb, nullptr, nullptr, scale);
    // v = x0 @ Wv^T
    conv_kernel<<<nX / 1024, 256, 0, stream>>>(x0, xh, nX);
    gemm_bt<false><<<ggrid, 256, 0, stream>>>(xh, nullptr, Wvh, nullptr, Vb, nullptr, nullptr, 1.0f);

    dim3 agrid(16, 8, 16);  // (q-tile, head, batch)
    attn_kernel<<<agrid, 256, 0, stream>>>(Qb, Kb, Vb, AOb);

    // out = attn_out @ Wu^T + bu   (fp32 out for pooling precision)
    gemm_bt<false><<<ggrid, 256, 0, stream>>>(AOb, nullptr, Wuh, nullptr, nullptr, outU, bu, 1.0f);

    pool_kernel<<<16, 1024, 0, stream>>>(outU, pooled);
    mlp_kernel<<<16, 64, 0, stream>>>(pooled, Wmlp, bmlp, out);
}

// Round 2
// 831.960 us; speedup vs baseline: 1.1517x; 1.1517x over previous
//
#include <hip/hip_runtime.h>

using u16 = unsigned short;
using short8 = __attribute__((ext_vector_type(8))) short;
using floatx4 = __attribute__((ext_vector_type(4))) float;

__device__ __forceinline__ u16 f2bf(float f) {
    union { float f; unsigned u; } v; v.f = f;
    unsigned u = v.u + 0x7FFFu + ((v.u >> 16) & 1u);
    return (u16)(u >> 16);
}
__device__ __forceinline__ float bf2f(u16 h) {
    union { unsigned u; float f; } v; v.u = ((unsigned)h) << 16;
    return v.f;
}

// async global->LDS, 16B per lane; LDS dest = wave-uniform base + lane*16
__device__ __forceinline__ void load_lds16(const u16* g, u16* l) {
    __builtin_amdgcn_global_load_lds(
        (const __attribute__((address_space(1))) unsigned int*)(g),
        (__attribute__((address_space(3))) unsigned int*)(l), 16, 0, 0);
}

// ---------------- conversions fp32 -> bf16 (plain and hi/lo split) ----------------
__global__ void conv_split_kernel(const float* __restrict__ src, u16* __restrict__ hi,
                                  u16* __restrict__ lo, int n) {
    int i = (blockIdx.x * blockDim.x + threadIdx.x) * 4;
    if (i >= n) return;
    float4 v = *reinterpret_cast<const float4*>(src + i);
    ushort4 h, l;
    h.x = f2bf(v.x); l.x = f2bf(v.x - bf2f(h.x));
    h.y = f2bf(v.y); l.y = f2bf(v.y - bf2f(h.y));
    h.z = f2bf(v.z); l.z = f2bf(v.z - bf2f(h.z));
    h.w = f2bf(v.w); l.w = f2bf(v.w - bf2f(h.w));
    *reinterpret_cast<ushort4*>(hi + i) = h;
    *reinterpret_cast<ushort4*>(lo + i) = l;
}

__global__ void conv_kernel(const float* __restrict__ src, u16* __restrict__ dst, int n) {
    int i = (blockIdx.x * blockDim.x + threadIdx.x) * 4;
    if (i >= n) return;
    float4 v = *reinterpret_cast<const float4*>(src + i);
    ushort4 h;
    h.x = f2bf(v.x); h.y = f2bf(v.y); h.z = f2bf(v.z); h.w = f2bf(v.w);
    *reinterpret_cast<ushort4*>(dst + i) = h;
}

// ---------------- GEMM: C[M,N] = A[M,K] @ B[N,K]^T  (bf16 in, fp32 acc) ----------
// 128x128 tile, BK=32, 256 threads (4 waves, 64x64/wave), global_load_lds staging.
// LDS plane layout (per 128x32 tile): slot (r, s) at u16 offset r*32 + s*8 holds
// global k-chunk c = s ^ (r&3) (XOR swizzle: contiguous global 64B per 4 lanes,
// 2-way-max bank pattern on ds_read_b128 fragment reads).
// SPLIT: hi+lo planes, C ~= Ah*Bh + Al*Bh + Ah*Bl.
// TRANS: write output transposed per (b,h): Vt[(b*8+h)*128 + d][l].
#define GK 1024
#define GN 1024

template<bool SPLIT, bool TRANS>
__global__ __launch_bounds__(256)
void gemm_bt(const u16* __restrict__ Ah, const u16* __restrict__ Al,
             const u16* __restrict__ Bh, const u16* __restrict__ Bl,
             u16* __restrict__ Cb, float* __restrict__ Cf,
             const float* __restrict__ bias, float scale,
             u16* __restrict__ Vt)
{
    constexpr int SM = TRANS ? 17408 : (SPLIT ? 16384 : 8192);
    __shared__ __align__(16) u16 smem[SM];

    const int tid  = threadIdx.x;
    const int lane = tid & 63, wave = tid >> 6;
    const int quad = lane >> 4, l15 = lane & 15;
    const int wr = wave >> 1, wc = wave & 1;
    const int bm = blockIdx.y * 128, bn = blockIdx.x * 128;

    floatx4 acc[4][4];
#pragma unroll
    for (int mt = 0; mt < 4; ++mt)
#pragma unroll
        for (int nt = 0; nt < 4; ++nt)
#pragma unroll
            for (int r = 0; r < 4; ++r) acc[mt][nt][r] = 0.f;

    // staging assignment
    const int cgl = (lane & 3) ^ ((lane >> 2) & 3);  // swizzled global chunk, lane-only
    const int rl  = lane >> 2;                        // row within 16-row group
    const u16* gplane; int rowbase; u16* lplane; int q0, nq;
    if (SPLIT) {
        gplane  = (wave == 0) ? Ah : (wave == 1) ? Al : (wave == 2) ? Bh : Bl;
        rowbase = (wave < 2) ? bm : bn;
        lplane  = smem + wave * 4096;
        q0 = 0; nq = 8;
    } else {
        gplane  = (wave < 2) ? Ah : Bh;
        rowbase = (wave < 2) ? bm : bn;
        lplane  = smem + (wave >> 1) * 4096;
        q0 = (wave & 1) * 4; nq = 4;
    }
    const u16* gbase = gplane + (size_t)(rowbase + rl) * GK + cgl * 8;

    const int s8 = (quad ^ (l15 & 3)) * 8;   // swizzled chunk offset for fragment reads
    const int AHo = 0, ALo = 4096;
    const int BHo = SPLIT ? 8192 : 4096, BLo = 12288;

    for (int kt = 0; kt < GK; kt += 32) {
        __syncthreads();
#pragma unroll
        for (int q = 0; q < (SPLIT ? 8 : 4); ++q) {
            int qq = q0 + q;
            load_lds16(gbase + (size_t)qq * 16 * GK + kt, lplane + qq * 512);
        }
        __syncthreads();

        short8 a_h[4], b_h[4];
#pragma unroll
        for (int mt = 0; mt < 4; ++mt) {
            int ra = wr * 64 + mt * 16 + l15;
            a_h[mt] = *reinterpret_cast<const short8*>(smem + AHo + ra * 32 + s8);
        }
#pragma unroll
        for (int nt = 0; nt < 4; ++nt) {
            int rb = wc * 64 + nt * 16 + l15;
            b_h[nt] = *reinterpret_cast<const short8*>(smem + BHo + rb * 32 + s8);
        }
#pragma unroll
        for (int mt = 0; mt < 4; ++mt)
#pragma unroll
            for (int nt = 0; nt < 4; ++nt)
                acc[mt][nt] = __builtin_amdgcn_mfma_f32_16x16x32_bf16(a_h[mt], b_h[nt], acc[mt][nt], 0, 0, 0);

        if (SPLIT) {
            short8 a_l[4], b_l[4];
#pragma unroll
            for (int mt = 0; mt < 4; ++mt) {
                int ra = wr * 64 + mt * 16 + l15;
                a_l[mt] = *reinterpret_cast<const short8*>(smem + ALo + ra * 32 + s8);
            }
#pragma unroll
            for (int nt = 0; nt < 4; ++nt) {
                int rb = wc * 64 + nt * 16 + l15;
                b_l[nt] = *reinterpret_cast<const short8*>(smem + BLo + rb * 32 + s8);
            }
#pragma unroll
            for (int mt = 0; mt < 4; ++mt)
#pragma unroll
                for (int nt = 0; nt < 4; ++nt) {
                    acc[mt][nt] = __builtin_amdgcn_mfma_f32_16x16x32_bf16(a_l[mt], b_h[nt], acc[mt][nt], 0, 0, 0);
                    acc[mt][nt] = __builtin_amdgcn_mfma_f32_16x16x32_bf16(a_h[mt], b_l[nt], acc[mt][nt], 0, 0, 0);
                }
        }
    }

    if (!TRANS) {
        // C/D layout: col = lane&15, row = quad*4 + reg
#pragma unroll
        for (int mt = 0; mt < 4; ++mt)
#pragma unroll
            for (int nt = 0; nt < 4; ++nt)
#pragma unroll
                for (int r = 0; r < 4; ++r) {
                    int row = bm + wr * 64 + mt * 16 + quad * 4 + r;
                    int col = bn + wc * 64 + nt * 16 + l15;
                    float v = acc[mt][nt][r] * scale;
                    if (bias) v += bias[col];
                    size_t off = (size_t)row * GN + col;
                    if (Cf) Cf[off] = v;
                    else Cb[off] = f2bf(v);
                }
    } else {
        // transpose 128x128 tile via LDS, write Vt[(b*8+h)*128 + d][l]
        __syncthreads();
#pragma unroll
        for (int mt = 0; mt < 4; ++mt)
#pragma unroll
            for (int nt = 0; nt < 4; ++nt)
#pragma unroll
                for (int r = 0; r < 4; ++r) {
                    int row_local = wr * 64 + mt * 16 + quad * 4 + r;
                    int col_local = wc * 64 + nt * 16 + l15;
                    smem[col_local * 136 + row_local] = f2bf(acc[mt][nt][r]);
                }
        __syncthreads();
        int b = bm >> 10, l0 = bm & 1023, h = blockIdx.x;
        int d = tid >> 1, rblk = (tid & 1) * 64;
        u16* gv = Vt + ((size_t)(b * 8 + h) * 128 + d) * 1024 + l0 + rblk;
#pragma unroll
        for (int v = 0; v < 8; ++v)
            *reinterpret_cast<short8*>(gv + v * 8) =
                *reinterpret_cast<const short8*>(smem + d * 136 + rblk + v * 8);
    }
}

// ---------------- fused flash attention ----------------
// grid (qt=16, h=8, b=16); block 256 = 4 waves; wave handles 16 q rows, 64-key tiles.
// Q,K pre-scaled by k^-0.25. V consumed via pre-transposed Vt[(b*8+h)*128+d][l].
#define LKS 136  // K lds stride (128+8)
#define LVS 72   // Vt lds stride (64+8)
#define LPS 72   // P lds stride (64+8)

__global__ __launch_bounds__(256)
void attn_kernel(const u16* __restrict__ Q, const u16* __restrict__ Kk,
                 const u16* __restrict__ Vt, u16* __restrict__ AO)
{
    __shared__ u16 Ks[64 * LKS];
    __shared__ u16 Vts[128 * LVS];
    __shared__ u16 Ps[4][16 * LPS];

    const int tid  = threadIdx.x;
    const int lane = tid & 63, wave = tid >> 6;
    const int quad = lane >> 4, l15 = lane & 15;
    const int qt = blockIdx.x, h = blockIdx.y, b = blockIdx.z;

    // Q fragments (A layout: m = lane&15, k = s*32 + quad*8 + j), kept in regs
    short8 qf[4];
    {
        int qrow = b * 1024 + qt * 64 + wave * 16 + l15;
        const u16* qp = Q + (size_t)qrow * 1024 + h * 128;
#pragma unroll
        for (int s = 0; s < 4; ++s)
            qf[s] = *reinterpret_cast<const short8*>(qp + s * 32 + quad * 8);
    }

    float m_r[4], l_r[4];
    floatx4 oacc[8];
#pragma unroll
    for (int r = 0; r < 4; ++r) { m_r[r] = -3.0e38f; l_r[r] = 0.f; }
#pragma unroll
    for (int nt = 0; nt < 8; ++nt)
#pragma unroll
        for (int r = 0; r < 4; ++r) oacc[nt][r] = 0.f;

    const u16* vtbase = Vt + (size_t)(b * 8 + h) * 128 * 1024;

    for (int kt2 = 0; kt2 < 16; ++kt2) {
        __syncthreads();  // protect restaging vs previous iteration's reads
        // stage K tile [64 keys x 128 dims]
#pragma unroll
        for (int i = 0; i < 4; ++i) {
            int chunk = tid + i * 256;
            int r = chunk >> 4, c = (chunk & 15) * 8;
            *reinterpret_cast<short8*>(&Ks[r * LKS + c]) =
                *reinterpret_cast<const short8*>(Kk + (size_t)(b * 1024 + kt2 * 64 + r) * 1024 + h * 128 + c);
        }
        // stage Vt tile [128 dims x 64 keys] (already transposed in global)
#pragma unroll
        for (int v = 0; v < 4; ++v) {
            int idx = tid + v * 256;
            int d = idx >> 3, kc = (idx & 7) * 8;
            *reinterpret_cast<short8*>(&Vts[d * LVS + kc]) =
                *reinterpret_cast<const short8*>(vtbase + (size_t)d * 1024 + kt2 * 64 + kc);
        }
        __syncthreads();

        // S = Q K^T  (16 x 64 per wave)
        floatx4 sacc[4];
#pragma unroll
        for (int nt = 0; nt < 4; ++nt)
#pragma unroll
            for (int r = 0; r < 4; ++r) sacc[nt][r] = 0.f;
#pragma unroll
        for (int s = 0; s < 4; ++s)
#pragma unroll
            for (int nt = 0; nt < 4; ++nt) {
                short8 bfr = *reinterpret_cast<const short8*>(&Ks[(nt * 16 + l15) * LKS + s * 32 + quad * 8]);
                sacc[nt] = __builtin_amdgcn_mfma_f32_16x16x32_bf16(qf[s], bfr, sacc[nt], 0, 0, 0);
            }

        // online softmax: row = quad*4 + r
        float alpha[4];
#pragma unroll
        for (int r = 0; r < 4; ++r) {
            float mx = sacc[0][r];
#pragma unroll
            for (int nt = 1; nt < 4; ++nt) mx = fmaxf(mx, sacc[nt][r]);
            mx = fmaxf(mx, __shfl_xor(mx, 1));
            mx = fmaxf(mx, __shfl_xor(mx, 2));
            mx = fmaxf(mx, __shfl_xor(mx, 4));
            mx = fmaxf(mx, __shfl_xor(mx, 8));
            float mn = fmaxf(m_r[r], mx);
            alpha[r] = __expf(m_r[r] - mn);
            m_r[r] = mn;
            float sum = 0.f;
#pragma unroll
            for (int nt = 0; nt < 4; ++nt) {
                float pv = __expf(sacc[nt][r] - mn);
                sacc[nt][r] = pv;
                sum += pv;
            }
            sum += __shfl_xor(sum, 1);
            sum += __shfl_xor(sum, 2);
            sum += __shfl_xor(sum, 4);
            sum += __shfl_xor(sum, 8);
            l_r[r] = l_r[r] * alpha[r] + sum;
        }
#pragma unroll
        for (int nt = 0; nt < 8; ++nt)
#pragma unroll
            for (int r = 0; r < 4; ++r) oacc[nt][r] *= alpha[r];

        // P: C-layout -> LDS -> A-layout
#pragma unroll
        for (int nt = 0; nt < 4; ++nt)
#pragma unroll
            for (int r = 0; r < 4; ++r)
                Ps[wave][(quad * 4 + r) * LPS + nt * 16 + l15] = f2bf(sacc[nt][r]);
        __syncthreads();

        // O += P V
#pragma unroll
        for (int ks = 0; ks < 2; ++ks) {
            short8 pa = *reinterpret_cast<const short8*>(&Ps[wave][l15 * LPS + ks * 32 + quad * 8]);
#pragma unroll
            for (int nt = 0; nt < 8; ++nt) {
                short8 bv = *reinterpret_cast<const short8*>(&Vts[(nt * 16 + l15) * LVS + ks * 32 + quad * 8]);
                oacc[nt] = __builtin_amdgcn_mfma_f32_16x16x32_bf16(pa, bv, oacc[nt], 0, 0, 0);
            }
        }
    }

    // epilogue: normalize and store bf16
#pragma unroll
    for (int r = 0; r < 4; ++r) {
        float inv = 1.0f / l_r[r];
        int row = b * 1024 + qt * 64 + wave * 16 + quad * 4 + r;
#pragma unroll
        for (int nt = 0; nt < 8; ++nt) {
            int col = h * 128 + nt * 16 + l15;
            AO[(size_t)row * 1024 + col] = f2bf(oacc[nt][r] * inv);
        }
    }
}

// ---------------- pooling: mean + max over L ----------------
__global__ void pool_kernel(const float* __restrict__ O, float* __restrict__ P) {
    int b = blockIdx.x, d = threadIdx.x;  // block 1024
    const float* p = O + (size_t)b * 1024 * 1024 + d;
    float s = 0.f, mx = -3.0e38f;
    for (int l = 0; l < 1024; ++l) {
        float v = p[(size_t)l * 1024];
        s += v;
        mx = fmaxf(mx, v);
    }
    P[b * 1024 + d] = s * (1.0f / 1024.0f) + mx;
}

// ---------------- final MLP: [16,1024] @ [64,1024]^T + bias ----------------
__global__ void mlp_kernel(const float* __restrict__ P, const float* __restrict__ W,
                           const float* __restrict__ bias, float* __restrict__ out) {
    int b = blockIdx.x, o = threadIdx.x;  // block 64
    const float* pr = P + b * 1024;
    const float* wr = W + o * 1024;
    float s = bias[o];
    for (int d = 0; d < 1024; ++d) s += pr[d] * wr[d];
    out[b * 64 + o] = s;
}

extern "C" void kernel_launch(void* const* d_in, const int* in_sizes, int n_in,
                              void* d_out, int out_size, void* d_ws, size_t ws_size,
                              hipStream_t stream) {
    const float* x0 = (const float*)d_in[0];
    const float* x1 = (const float*)d_in[1];
    const float* x2 = (const float*)d_in[2];
    const float* Wk = (const float*)d_in[5];
    const float* Wq = (const float*)d_in[6];
    const float* Wv = (const float*)d_in[7];
    const float* Wu = (const float*)d_in[8];
    const float* bu = (const float*)d_in[9];
    const float* Wmlp = (const float*)d_in[10];
    const float* bmlp = (const float*)d_in[11];
    float* out = (float*)d_out;

    char* ws = (char*)d_ws;
    const size_t MB32 = 33554432ull;
    u16* xh = (u16*)(ws);
    u16* xl = (u16*)(ws + MB32);
    float* outU = (float*)(ws);  // overlay, used after xh/xl are dead
    size_t wo = 2 * MB32;
    u16* Wkh = (u16*)(ws + wo); wo += 2097152;
    u16* Wkl = (u16*)(ws + wo); wo += 2097152;
    u16* Wqh = (u16*)(ws + wo); wo += 2097152;
    u16* Wql = (u16*)(ws + wo); wo += 2097152;
    u16* Wvh = (u16*)(ws + wo); wo += 2097152;
    u16* Wuh = (u16*)(ws + wo); wo += 2097152;
    u16* Qb = (u16*)(ws + wo); wo += MB32;
    u16* Kb = (u16*)(ws + wo); wo += MB32;
    u16* Vt = (u16*)(ws + wo); wo += MB32;
    u16* AOb = (u16*)(ws + wo); wo += MB32;
    float* pooled = (float*)(ws + wo); wo += 65536;
    if (ws_size < wo) return;

    const float scale = 0.29730177875068026f;  // 128^(-0.25)
    const int nX = 16 * 1024 * 1024;
    const int nW = 1024 * 1024;

    conv_split_kernel<<<nW / 1024, 256, 0, stream>>>(Wk, Wkh, Wkl, nW);
    conv_split_kernel<<<nW / 1024, 256, 0, stream>>>(Wq, Wqh, Wql, nW);
    conv_kernel<<<nW / 1024, 256, 0, stream>>>(Wv, Wvh, nW);
    conv_kernel<<<nW / 1024, 256, 0, stream>>>(Wu, Wuh, nW);

    dim3 ggrid(8, 128);  // N/128, M/128
    // q = (x2 @ Wk^T) * scale   [split for accuracy: feeds softmax logits]
    conv_split_kernel<<<nX / 1024, 256, 0, stream>>>(x2, xh, xl, nX);
    gemm_bt<true, false><<<ggrid, 256, 0, stream>>>(xh, xl, Wkh, Wkl, Qb, nullptr, nullptr, scale, nullptr);
    // k = (x1 @ Wq^T) * scale
    conv_split_kernel<<<nX / 1024, 256, 0, stream>>>(x1, xh, xl, nX);
    gemm_bt<true, false><<<ggrid, 256, 0, stream>>>(xh, xl, Wqh, Wql, Kb, nullptr, nullptr, scale, nullptr);
    // v = x0 @ Wv^T, written transposed per (b,h): Vt[(b*8+h)*128+d][l]
    conv_kernel<<<nX / 1024, 256, 0, stream>>>(x0, xh, nX);
    gemm_bt<false, true><<<ggrid, 256, 0, stream>>>(xh, nullptr, Wvh, nullptr, nullptr, nullptr, nullptr, 1.0f, Vt);

    dim3 agrid(16, 8, 16);  // (q-tile, head, batch)
    attn_kernel<<<agrid, 256, 0, stream>>>(Qb, Kb, Vt, AOb);

    // out = attn_out @ Wu^T + bu   (fp32 out for pooling precision)
    gemm_bt<false, false><<<ggrid, 256, 0, stream>>>(AOb, nullptr, Wuh, nullptr, nullptr, outU, bu, 1.0f, nullptr);

    pool_kernel<<<16, 1024, 0, stream>>>(outU, pooled);
    mlp_kernel<<<16, 64, 0, stream>>>(pooled, Wmlp, bmlp, out);
}